// Round 1
// 142.880 us; speedup vs baseline: 1.1210x; 1.1210x over previous
//
#include <hip/hip_runtime.h>

// Head attention forward, MI355X gfx950.
// B=8, T=2048, C=1024, H=64. Scale C^-0.5*log2e folded into q at gemm epilogue.
// R7 = R6 with flash restructured for occupancy: fixed-max softmax means o,l are
// plain sums over keys -> split each q-tile's key range into 4-step (256-key)
// chunks. Block = 4 waves (4 consecutive q-tiles share nst=u+1 steps) x 1 chunk.
// Grid 144x8 = 1152 blocks, 4608 waves of <=4 steps (was 1024 waves of <=32).
// Partials (f32 o[16][64] + l[16]) -> ws; freduce sums <=8 partials + normalizes.
//
// ws layout (u16/bf16):
//   [0, BTH) k [b][t][h] | [BTH, 2BTH) q' | [2BTH, 3BTH) vt [b][h][t]
//   [3BTH, +192K) Wct [n][k]  n: 0..63=Wk, 64..127=Wq, 128..191=Wv
//   then f32 partials: slot = (b*128+qt)*8 + c, 1040 f32 each (~34 MB)

#define B_ 8
#define T_ 2048
#define C_ 1024
#define H_ 64
#define BTH (B_ * T_ * H_)

typedef unsigned short u16;
typedef float f32x4 __attribute__((ext_vector_type(4)));
typedef __bf16 bf16x8 __attribute__((ext_vector_type(8)));
#define AS1 __attribute__((address_space(1)))
#define AS3 __attribute__((address_space(3)))

__device__ __forceinline__ u16 f2bf(float f) {
  union { float f; unsigned u; } c; c.f = f;
  unsigned u = c.u;
  return (u16)((u + 0x7FFFu + ((u >> 16) & 1u)) >> 16);  // RNE
}

__device__ __forceinline__ bf16x8 cvt8(const float4 a, const float4 b) {
  bf16x8 r;
  r[0] = (__bf16)a.x; r[1] = (__bf16)a.y; r[2] = (__bf16)a.z; r[3] = (__bf16)a.w;
  r[4] = (__bf16)b.x; r[5] = (__bf16)b.y; r[6] = (__bf16)b.z; r[7] = (__bf16)b.w;
  return r;
}

// ---------------------------------------------------------------------------
// wpack: Wct[g*64+h][k] = W_g[k][h], bf16. grid (3,16), block 256.
// ---------------------------------------------------------------------------
__global__ __launch_bounds__(256)
void wpack(const float* __restrict__ Wk, const float* __restrict__ Wq,
           const float* __restrict__ Wv, u16* __restrict__ Wct) {
  const int g  = blockIdx.x;
  const int k0 = blockIdx.y * 64;
  const float* __restrict__ W = (g == 0) ? Wk : (g == 1) ? Wq : Wv;
#pragma unroll
  for (int it = 0; it < 16; ++it) {
    const int idx = it * 256 + threadIdx.x;
    const int kk = k0 + (idx >> 6), h = idx & 63;
    Wct[(size_t)(g * 64 + h) * C_ + kk] = f2bf(W[(size_t)kk * H_ + h]);
  }
}

// ---------------------------------------------------------------------------
// qkv_gemm: grid (512), block 256 (4 waves). Tile 32 rows x 192 cols, BK=128.
// (unchanged from R6)
// ---------------------------------------------------------------------------
__global__ __launch_bounds__(256)
void qkv_gemm(const float* __restrict__ x, const u16* __restrict__ Wct,
              u16* __restrict__ ws) {
  __shared__ u16 As[32 * 128];  // 8 KB
  const int tid  = threadIdx.x;
  const int wave = tid >> 6, lane = tid & 63;
  const int l15 = lane & 15, quad = lane >> 4;
  const int r0 = blockIdx.x * 32;
  // staging
  const int srow = tid >> 3, sseg = tid & 7;
  const float* __restrict__ xsrc = x + (size_t)(r0 + srow) * C_ + sseg * 16;
  u16* const wdst0 = As + srow * 128 + ((2 * sseg)     ^ (srow & 15)) * 8;
  u16* const wdst1 = As + srow * 128 + ((2 * sseg + 1) ^ (srow & 15)) * 8;
  // compute
  const u16* __restrict__ wp = Wct + (size_t)(wave * 48 + l15) * C_ + quad * 8;
  const u16* const ard0 = As + l15 * 128;          // m=0 row base
  const u16* const ard1 = As + (16 + l15) * 128;   // m=1
  const f32x4 z = {0.f, 0.f, 0.f, 0.f};
  f32x4 acc[2][3];
#pragma unroll
  for (int m = 0; m < 2; ++m)
#pragma unroll
    for (int ni = 0; ni < 3; ++ni) acc[m][ni] = z;

#pragma unroll 1
  for (int ks = 0; ks < 8; ++ks) {
    const int k0 = ks * 128;
    float4 xa0 = *(const float4*)(xsrc + k0);
    float4 xa1 = *(const float4*)(xsrc + k0 + 4);
    float4 xa2 = *(const float4*)(xsrc + k0 + 8);
    float4 xa3 = *(const float4*)(xsrc + k0 + 12);
    bf16x8 Bf[3][4];
#pragma unroll
    for (int ni = 0; ni < 3; ++ni)
#pragma unroll
      for (int f = 0; f < 4; ++f)
        Bf[ni][f] = *(const bf16x8*)(wp + (size_t)ni * 16 * C_ + k0 + f * 32);
    __syncthreads();  // all waves done reading previous As
    *(bf16x8*)wdst0 = cvt8(xa0, xa1);
    *(bf16x8*)wdst1 = cvt8(xa2, xa3);
    __syncthreads();  // staged data visible
#pragma unroll
    for (int f = 0; f < 4; ++f) {
      const int co = (((4 * f + quad) ^ l15) * 8);
      const bf16x8 a0 = *(const bf16x8*)(ard0 + co);
      const bf16x8 a1 = *(const bf16x8*)(ard1 + co);
#pragma unroll
      for (int ni = 0; ni < 3; ++ni) {
        acc[0][ni] = __builtin_amdgcn_mfma_f32_16x16x32_bf16(a0, Bf[ni][f], acc[0][ni], 0, 0, 0);
        acc[1][ni] = __builtin_amdgcn_mfma_f32_16x16x32_bf16(a1, Bf[ni][f], acc[1][ni], 0, 0, 0);
      }
    }
  }
  // epilogue: col = wave*48 + ni*16 + l15 (g=col>>6 wave-uniform per ni)
  const float SCLL = 0.03125f * 1.44269504088896f;  // C^-0.5 * log2(e) -> q
  const int bb = r0 >> 11;
#pragma unroll
  for (int m = 0; m < 2; ++m) {
    const int rowg = r0 + m * 16;
    const int tb = (rowg & 2047) + quad * 4;
#pragma unroll
    for (int ni = 0; ni < 3; ++ni) {
      const int col = wave * 48 + ni * 16 + l15;
      const int g = col >> 6, h = col & 63;
      f32x4 a = acc[m][ni];
      if (g == 1) { a[0] *= SCLL; a[1] *= SCLL; a[2] *= SCLL; a[3] *= SCLL; }
      if (g < 2) {
        u16* op = ws + (size_t)g * BTH + (size_t)(rowg + quad * 4) * H_ + h;
#pragma unroll
        for (int r = 0; r < 4; ++r) op[(size_t)r * H_] = f2bf(a[r]);
      } else {
        uint2 pk;
        pk.x = (unsigned)f2bf(a[0]) | ((unsigned)f2bf(a[1]) << 16);
        pk.y = (unsigned)f2bf(a[2]) | ((unsigned)f2bf(a[3]) << 16);
        *(uint2*)(ws + (size_t)2 * BTH + (size_t)(bb * H_ + h) * T_ + tb) = pk;
      }
    }
  }
}

// ---------------------------------------------------------------------------
// flash: grid (144, 8), block 256 (4 waves). Work item = (b, u, c):
//   q-tiles qt = 4u+wv (wv=0..3) all have nst = u+1 64-key steps; chunk c
//   covers steps [4c, min(4c+4, u+1)). Chunk table over bx in [0,144):
//   off(c) = 34c - 2c^2, u = 4c + (bx - off(c)); bx reversed so the
//   all-4-step deep chunks dispatch first.
// K/V staged via global_load_lds into double-buffered swizzled LDS
// (chunk' = chunk ^ (row&7)); stage(next) issued before compute(cur);
// one __syncthreads per step. Fixed-max softmax (q pre-scaled) => o,l are
// plain sums; partials written to ws, combined by freduce.
// ---------------------------------------------------------------------------
__global__ __launch_bounds__(256)
void flash(const u16* __restrict__ ws, float* __restrict__ fpart) {
  __shared__ u16 Ks[2][64 * 64];   // 8 KB each
  __shared__ u16 Vs[2][64 * 64];
  __shared__ __bf16 Pt[4][16 * 72];
  const u16* __restrict__ kg = ws;
  const u16* __restrict__ qg = ws + BTH;
  const u16* __restrict__ vt = ws + (size_t)2 * BTH;
  const int b  = blockIdx.y;
  const int bx = 143 - (int)blockIdx.x;  // deep (all-4-step) chunks first
  int c = 0;
#pragma unroll
  for (int t = 1; t < 8; ++t)
    if (34 * t - 2 * t * t <= bx) c = t;
  const int u = 4 * c + (bx - (34 * c - 2 * c * c));
  const int tid  = threadIdx.x;
  const int wv   = tid >> 6;
  const int lane = tid & 63;
  const int l15  = lane & 15, quad = lane >> 4;
  const int qt   = 4 * u + wv;
  const int t0   = qt * 16;
  const int st0  = 4 * c;
  const int stE  = (st0 + 4 < u + 1) ? st0 + 4 : u + 1;
  const u16* kb0 = kg + (size_t)b * T_ * H_;
  const u16* vb0 = vt + (size_t)b * H_ * T_;
  // staging geometry: slot = jj*256 + tid; row = slot>>3 = jj*32+(tid>>3)
  const int srow = tid >> 3, scp = tid & 7;
  // q fragments (pre-scaled by C^-0.5*log2e in gemm)
  const u16* qrow = qg + ((size_t)(b * T_ + t0 + l15)) * H_ + quad * 8;
  const bf16x8 qf0 = *(const bf16x8*)qrow;
  const bf16x8 qf1 = *(const bf16x8*)(qrow + 32);
  __bf16* pt = &Pt[wv][0];
  const f32x4 z = {0.f, 0.f, 0.f, 0.f};
  f32x4 o[4];
  float lr[4] = {0.f, 0.f, 0.f, 0.f};
#pragma unroll
  for (int hi = 0; hi < 4; ++hi) o[hi] = z;

  // prologue: stage step st0 into buf 0
  {
    const int s00 = st0 * 64;
#pragma unroll
    for (int jj = 0; jj < 2; ++jj) {
      const int row = jj * 32 + srow;
      const int sc  = scp ^ (row & 7);
      __builtin_amdgcn_global_load_lds(
          (const AS1 unsigned*)(kb0 + (size_t)(s00 + row) * H_ + sc * 8),
          (AS3 unsigned*)(&Ks[0][(jj * 256 + tid) * 8]), 16, 0, 0);
      __builtin_amdgcn_global_load_lds(
          (const AS1 unsigned*)(vb0 + (size_t)row * T_ + s00 + sc * 8),
          (AS3 unsigned*)(&Vs[0][(jj * 256 + tid) * 8]), 16, 0, 0);
    }
  }
  __syncthreads();

#pragma unroll 1
  for (int st = st0; st < stE; ++st) {
    const int cur = (st - st0) & 1;
    if (st + 1 < stE) {  // stage next into other buffer
      const int s1 = (st + 1) * 64;
#pragma unroll
      for (int jj = 0; jj < 2; ++jj) {
        const int row = jj * 32 + srow;
        const int sc  = scp ^ (row & 7);
        __builtin_amdgcn_global_load_lds(
            (const AS1 unsigned*)(kb0 + (size_t)(s1 + row) * H_ + sc * 8),
            (AS3 unsigned*)(&Ks[cur ^ 1][(jj * 256 + tid) * 8]), 16, 0, 0);
        __builtin_amdgcn_global_load_lds(
            (const AS1 unsigned*)(vb0 + (size_t)row * T_ + s1 + sc * 8),
            (AS3 unsigned*)(&Vs[cur ^ 1][(jj * 256 + tid) * 8]), 16, 0, 0);
      }
    }
    // ---- compute on buf cur ----
    const u16* Kc = &Ks[cur][0];
    const u16* Vc = &Vs[cur][0];
    const int sw = (l15 & 7);
    f32x4 s[4];
#pragma unroll
    for (int ni = 0; ni < 4; ++ni) {
      const u16* kr = Kc + (ni * 16 + l15) * 64;
      const bf16x8 k0 = *(const bf16x8*)(kr + ((quad       ^ sw) * 8));
      const bf16x8 k1 = *(const bf16x8*)(kr + (((4 + quad) ^ sw) * 8));
      s[ni] = __builtin_amdgcn_mfma_f32_16x16x32_bf16(qf0, k0, z, 0, 0, 0);
      s[ni] = __builtin_amdgcn_mfma_f32_16x16x32_bf16(qf1, k1, s[ni], 0, 0, 0);
    }
    if (st == u) {  // causal mask (only the tile's final step crosses diagonal)
      const int s0 = st * 64;
#pragma unroll
      for (int ni = 0; ni < 4; ++ni)
#pragma unroll
        for (int r = 0; r < 4; ++r)
          if (s0 + ni * 16 + l15 > t0 + quad * 4 + r) s[ni][r] = -1e30f;
    }
    float p[4][4];
#pragma unroll
    for (int ni = 0; ni < 4; ++ni)
#pragma unroll
      for (int r = 0; r < 4; ++r) p[ni][r] = __builtin_amdgcn_exp2f(s[ni][r]);
#pragma unroll
    for (int r = 0; r < 4; ++r)
      lr[r] += (p[0][r] + p[1][r]) + (p[2][r] + p[3][r]);
    // P: C-layout -> A-layout via per-wave LDS (wave-local fence only)
#pragma unroll
    for (int ni = 0; ni < 4; ++ni)
#pragma unroll
      for (int r = 0; r < 4; ++r)
        pt[(quad * 4 + r) * 72 + ni * 16 + l15] = (__bf16)p[ni][r];
    asm volatile("s_waitcnt lgkmcnt(0)" ::: "memory");
    const bf16x8 pa0 = *(const bf16x8*)(pt + l15 * 72 + quad * 8);
    const bf16x8 pa1 = *(const bf16x8*)(pt + l15 * 72 + 32 + quad * 8);
    asm volatile("" ::: "memory");
#pragma unroll
    for (int hi = 0; hi < 4; ++hi) {
      const u16* vr = Vc + (hi * 16 + l15) * 64;
      const bf16x8 v0 = *(const bf16x8*)(vr + ((quad       ^ sw) * 8));
      const bf16x8 v1 = *(const bf16x8*)(vr + (((4 + quad) ^ sw) * 8));
      o[hi] = __builtin_amdgcn_mfma_f32_16x16x32_bf16(pa0, v0, o[hi], 0, 0, 0);
      o[hi] = __builtin_amdgcn_mfma_f32_16x16x32_bf16(pa1, v1, o[hi], 0, 0, 0);
    }
    __syncthreads();  // everyone done with cur; next-glds drained
  }
  // epilogue: row-sum lr across the 16 lanes of each quad, write f32 partial
#pragma unroll
  for (int d = 1; d < 16; d <<= 1)
#pragma unroll
    for (int r = 0; r < 4; ++r) lr[r] += __shfl_xor(lr[r], d, 64);
  float* po = fpart + (size_t)((b * 128 + qt) * 8 + c) * 1040;
#pragma unroll
  for (int hi = 0; hi < 4; ++hi)
#pragma unroll
    for (int r = 0; r < 4; ++r)
      po[(quad * 4 + r) * 64 + hi * 16 + l15] = o[hi][r];
  if (l15 == 0) {
#pragma unroll
    for (int r = 0; r < 4; ++r) po[1024 + quad * 4 + r] = lr[r];
  }
}

// ---------------------------------------------------------------------------
// freduce: grid (128, 8), block 256. Block (qt, b): sum nc = (qt>>4)+1 chunk
// partials (deterministic order) and normalize by l. Thread t owns float4 at
// element 4t: row = t>>4, cols (4t)&63.
// ---------------------------------------------------------------------------
__global__ __launch_bounds__(256)
void freduce(const float* __restrict__ fpart, float* __restrict__ out) {
  const int qt  = blockIdx.x;
  const int b   = blockIdx.y;
  const int tid = threadIdx.x;
  const int nc  = (qt >> 4) + 1;  // ceil(((qt>>2)+1)/4)
  const float* __restrict__ pb = fpart + (size_t)(b * 128 + qt) * 8 * 1040;
  __shared__ float ls[16];
  if (tid < 16) {
    float s = 0.f;
#pragma unroll 1
    for (int i = 0; i < nc; ++i) s += pb[(size_t)i * 1040 + 1024 + tid];
    ls[tid] = s;
  }
  __syncthreads();
  f32x4 a = {0.f, 0.f, 0.f, 0.f};
#pragma unroll 1
  for (int i = 0; i < nc; ++i)
    a += *(const f32x4*)(pb + (size_t)i * 1040 + tid * 4);
  const float inv = 1.0f / ls[tid >> 4];
  a[0] *= inv; a[1] *= inv; a[2] *= inv; a[3] *= inv;
  *(f32x4*)(out + (size_t)(b * T_ + qt * 16 + (tid >> 4)) * H_ + ((tid * 4) & 63)) = a;
}

extern "C" void kernel_launch(void* const* d_in, const int* in_sizes, int n_in,
                              void* d_out, int out_size, void* d_ws, size_t ws_size,
                              hipStream_t stream) {
  const float* x  = (const float*)d_in[0];
  const float* Wk = (const float*)d_in[1];
  const float* Wq = (const float*)d_in[2];
  const float* Wv = (const float*)d_in[3];
  u16*   ws  = (u16*)d_ws;
  u16*   Wct = ws + (size_t)3 * BTH;
  float* fpart = (float*)(ws + (size_t)3 * BTH + 192 * 1024);  // 16B-aligned
  float* out = (float*)d_out;
  wpack<<<dim3(3, 16), 256, 0, stream>>>(Wk, Wq, Wv, Wct);
  qkv_gemm<<<dim3(512), 256, 0, stream>>>(x, Wct, ws);
  flash<<<dim3(144, B_), 256, 0, stream>>>(ws, fpart);
  freduce<<<dim3(128, B_), 256, 0, stream>>>(fpart, out);
}

// Round 2
// 139.906 us; speedup vs baseline: 1.1448x; 1.0213x over previous
//
#include <hip/hip_runtime.h>

// Head attention forward, MI355X gfx950.
// B=8, T=2048, C=1024, H=64. Scale C^-0.5*log2e folded into q at gemm epilogue.
// R8 = R7 with qkv_gemm rewritten: 64x192 tile (grid 256 = 1 block/CU),
// double-buffered LDS, ONE raw s_barrier per K-step (lgkmcnt(0) only -- no
// vmcnt drain, so prefetches survive barriers), x prefetched 2 steps ahead
// into alternating reg sets, B-frags issued before x (vmcnt wait on B leaves
// x outstanding), 48 MFMA/wave/barrier. flash/freduce/wpack unchanged from R7.
//
// ws layout (u16/bf16):
//   [0, BTH) k [b][t][h] | [BTH, 2BTH) q' | [2BTH, 3BTH) vt [b][h][t]
//   [3BTH, +192K) Wct [n][k]  n: 0..63=Wk, 64..127=Wq, 128..191=Wv
//   then f32 partials: slot = (b*128+qt)*8 + c, 1040 f32 each (~34 MB)

#define B_ 8
#define T_ 2048
#define C_ 1024
#define H_ 64
#define BTH (B_ * T_ * H_)

typedef unsigned short u16;
typedef float f32x4 __attribute__((ext_vector_type(4)));
typedef __bf16 bf16x8 __attribute__((ext_vector_type(8)));
#define AS1 __attribute__((address_space(1)))
#define AS3 __attribute__((address_space(3)))

__device__ __forceinline__ u16 f2bf(float f) {
  union { float f; unsigned u; } c; c.f = f;
  unsigned u = c.u;
  return (u16)((u + 0x7FFFu + ((u >> 16) & 1u)) >> 16);  // RNE
}

__device__ __forceinline__ bf16x8 cvt8(const float4 a, const float4 b) {
  bf16x8 r;
  r[0] = (__bf16)a.x; r[1] = (__bf16)a.y; r[2] = (__bf16)a.z; r[3] = (__bf16)a.w;
  r[4] = (__bf16)b.x; r[5] = (__bf16)b.y; r[6] = (__bf16)b.z; r[7] = (__bf16)b.w;
  return r;
}

// barrier with LDS-visibility only: no vmcnt drain (prefetches stay in flight)
#define GBAR() do {                                        \
    asm volatile("s_waitcnt lgkmcnt(0)" ::: "memory");     \
    __builtin_amdgcn_s_barrier();                          \
    __builtin_amdgcn_sched_barrier(0);                     \
  } while (0)

// ---------------------------------------------------------------------------
// wpack: Wct[g*64+h][k] = W_g[k][h], bf16. grid (3,16), block 256.
// ---------------------------------------------------------------------------
__global__ __launch_bounds__(256)
void wpack(const float* __restrict__ Wk, const float* __restrict__ Wq,
           const float* __restrict__ Wv, u16* __restrict__ Wct) {
  const int g  = blockIdx.x;
  const int k0 = blockIdx.y * 64;
  const float* __restrict__ W = (g == 0) ? Wk : (g == 1) ? Wq : Wv;
#pragma unroll
  for (int it = 0; it < 16; ++it) {
    const int idx = it * 256 + threadIdx.x;
    const int kk = k0 + (idx >> 6), h = idx & 63;
    Wct[(size_t)(g * 64 + h) * C_ + kk] = f2bf(W[(size_t)kk * H_ + h]);
  }
}

// ---------------------------------------------------------------------------
// qkv_gemm: grid (256), block 256 (4 waves). Tile 64 rows x 192 cols, BK=128.
// Wave w: cols 48w..48w+47 (3 n-tiles) x 4 m-tiles (rows 0-63).
// LDS A: bf16 [2 buf][64 rows][16 chunks of 8], chunk c at c' = c ^ (row&15).
//   stage: thread t: row=t>>2, sseg=t&3 -> chunks 4sseg..4sseg+3 (8-lane/group
//   bank-uniform). read: frag(m,f): row=m*16+l15, chunk (4f+quad)^l15.
// Schedule per step ks (one GBAR each):
//   [issue B[ks] L2 loads][issue x[ks+2] HBM loads][ds_read+48 MFMA on buf cur]
//   [cvt x[ks+1] (already vmcnt-forced by B wait) + ds_write buf nxt][GBAR]
// ---------------------------------------------------------------------------
__global__ __launch_bounds__(256)
void qkv_gemm(const float* __restrict__ x, const u16* __restrict__ Wct,
              u16* __restrict__ ws) {
  __shared__ u16 As[2][64 * 128];  // 32 KB
  const int tid  = threadIdx.x;
  const int wave = tid >> 6, lane = tid & 63;
  const int l15 = lane & 15, quad = lane >> 4;
  const int r0 = blockIdx.x * 64;
  // staging: 4 threads per row, each 32 f32 = 4 chunks of 8
  const int srow = tid >> 2, sseg = tid & 3;
  const int swz = srow & 15;
  const float* __restrict__ xsrc = x + (size_t)(r0 + srow) * C_ + sseg * 32;
  u16* wd0[4]; u16* wd1[4];
#pragma unroll
  for (int jj = 0; jj < 4; ++jj) {
    const int c = ((4 * sseg + jj) ^ swz) * 8;
    wd0[jj] = &As[0][srow * 128 + c];
    wd1[jj] = &As[1][srow * 128 + c];
  }
  // compute-side bases
  const u16* __restrict__ wp = Wct + (size_t)(wave * 48 + l15) * C_ + quad * 8;
  const f32x4 z = {0.f, 0.f, 0.f, 0.f};
  f32x4 acc[4][3];
#pragma unroll
  for (int m = 0; m < 4; ++m)
#pragma unroll
    for (int ni = 0; ni < 3; ++ni) acc[m][ni] = z;

  float4 xA[8], xB[8];
  // prologue: x[0] -> As[0]; issue x[1]
#pragma unroll
  for (int j = 0; j < 8; ++j) xA[j] = *(const float4*)(xsrc + j * 4);
#pragma unroll
  for (int jj = 0; jj < 4; ++jj)
    *(bf16x8*)wd0[jj] = cvt8(xA[2 * jj], xA[2 * jj + 1]);
#pragma unroll
  for (int j = 0; j < 8; ++j) xB[j] = *(const float4*)(xsrc + 128 + j * 4);
  GBAR();

#pragma unroll
  for (int kp = 0; kp < 4; ++kp) {
    // ---- even step ks=2kp: read As[0]; write As[1] <- xB(x[ks+1]);
    //      prefetch xA <- x[ks+2] ----
    {
      const int k0 = (2 * kp) * 128;
      bf16x8 Bf[3][4];
#pragma unroll
      for (int ni = 0; ni < 3; ++ni)
#pragma unroll
        for (int f = 0; f < 4; ++f)
          Bf[ni][f] = *(const bf16x8*)(wp + (size_t)ni * 16 * C_ + k0 + f * 32);
      if (kp < 3) {
#pragma unroll
        for (int j = 0; j < 8; ++j)
          xA[j] = *(const float4*)(xsrc + k0 + 256 + j * 4);
      }
#pragma unroll
      for (int f = 0; f < 4; ++f) {
        const int co = ((4 * f + quad) ^ l15) * 8;
#pragma unroll
        for (int m = 0; m < 4; ++m) {
          const bf16x8 a = *(const bf16x8*)(&As[0][(m * 16 + l15) * 128 + co]);
#pragma unroll
          for (int ni = 0; ni < 3; ++ni)
            acc[m][ni] = __builtin_amdgcn_mfma_f32_16x16x32_bf16(a, Bf[ni][f], acc[m][ni], 0, 0, 0);
        }
      }
#pragma unroll
      for (int jj = 0; jj < 4; ++jj)
        *(bf16x8*)wd1[jj] = cvt8(xB[2 * jj], xB[2 * jj + 1]);
      GBAR();
    }
    // ---- odd step ks=2kp+1: read As[1]; write As[0] <- xA(x[ks+1]);
    //      prefetch xB <- x[ks+2] ----
    {
      const int k0 = (2 * kp + 1) * 128;
      bf16x8 Bf[3][4];
#pragma unroll
      for (int ni = 0; ni < 3; ++ni)
#pragma unroll
        for (int f = 0; f < 4; ++f)
          Bf[ni][f] = *(const bf16x8*)(wp + (size_t)ni * 16 * C_ + k0 + f * 32);
      if (kp < 3) {
#pragma unroll
        for (int j = 0; j < 8; ++j)
          xB[j] = *(const float4*)(xsrc + k0 + 256 + j * 4);
      }
#pragma unroll
      for (int f = 0; f < 4; ++f) {
        const int co = ((4 * f + quad) ^ l15) * 8;
#pragma unroll
        for (int m = 0; m < 4; ++m) {
          const bf16x8 a = *(const bf16x8*)(&As[1][(m * 16 + l15) * 128 + co]);
#pragma unroll
          for (int ni = 0; ni < 3; ++ni)
            acc[m][ni] = __builtin_amdgcn_mfma_f32_16x16x32_bf16(a, Bf[ni][f], acc[m][ni], 0, 0, 0);
        }
      }
      if (kp < 3) {
#pragma unroll
        for (int jj = 0; jj < 4; ++jj)
          *(bf16x8*)wd0[jj] = cvt8(xA[2 * jj], xA[2 * jj + 1]);
      }
      GBAR();
    }
  }
  // epilogue: col = wave*48 + ni*16 + l15 (g=col>>6 wave-uniform per ni)
  const float SCLL = 0.03125f * 1.44269504088896f;  // C^-0.5 * log2(e) -> q
  const int bb = r0 >> 11;
#pragma unroll
  for (int m = 0; m < 4; ++m) {
    const int rowg = r0 + m * 16;
    const int tb = (rowg & 2047) + quad * 4;
#pragma unroll
    for (int ni = 0; ni < 3; ++ni) {
      const int col = wave * 48 + ni * 16 + l15;
      const int g = col >> 6, h = col & 63;
      f32x4 a = acc[m][ni];
      if (g == 1) { a[0] *= SCLL; a[1] *= SCLL; a[2] *= SCLL; a[3] *= SCLL; }
      if (g < 2) {
        u16* op = ws + (size_t)g * BTH + (size_t)(rowg + quad * 4) * H_ + h;
#pragma unroll
        for (int r = 0; r < 4; ++r) op[(size_t)r * H_] = f2bf(a[r]);
      } else {
        uint2 pk;
        pk.x = (unsigned)f2bf(a[0]) | ((unsigned)f2bf(a[1]) << 16);
        pk.y = (unsigned)f2bf(a[2]) | ((unsigned)f2bf(a[3]) << 16);
        *(uint2*)(ws + (size_t)2 * BTH + (size_t)(bb * H_ + h) * T_ + tb) = pk;
      }
    }
  }
}

// ---------------------------------------------------------------------------
// flash: grid (144, 8), block 256 (4 waves). Work item = (b, u, c):
//   q-tiles qt = 4u+wv (wv=0..3) all have nst = u+1 64-key steps; chunk c
//   covers steps [4c, min(4c+4, u+1)). Chunk table over bx in [0,144):
//   off(c) = 34c - 2c^2, u = 4c + (bx - off(c)); bx reversed so the
//   all-4-step deep chunks dispatch first.
// (unchanged from R7)
// ---------------------------------------------------------------------------
__global__ __launch_bounds__(256)
void flash(const u16* __restrict__ ws, float* __restrict__ fpart) {
  __shared__ u16 Ks[2][64 * 64];   // 8 KB each
  __shared__ u16 Vs[2][64 * 64];
  __shared__ __bf16 Pt[4][16 * 72];
  const u16* __restrict__ kg = ws;
  const u16* __restrict__ qg = ws + BTH;
  const u16* __restrict__ vt = ws + (size_t)2 * BTH;
  const int b  = blockIdx.y;
  const int bx = 143 - (int)blockIdx.x;  // deep (all-4-step) chunks first
  int c = 0;
#pragma unroll
  for (int t = 1; t < 8; ++t)
    if (34 * t - 2 * t * t <= bx) c = t;
  const int u = 4 * c + (bx - (34 * c - 2 * c * c));
  const int tid  = threadIdx.x;
  const int wv   = tid >> 6;
  const int lane = tid & 63;
  const int l15  = lane & 15, quad = lane >> 4;
  const int qt   = 4 * u + wv;
  const int t0   = qt * 16;
  const int st0  = 4 * c;
  const int stE  = (st0 + 4 < u + 1) ? st0 + 4 : u + 1;
  const u16* kb0 = kg + (size_t)b * T_ * H_;
  const u16* vb0 = vt + (size_t)b * H_ * T_;
  // staging geometry: slot = jj*256 + tid; row = slot>>3 = jj*32+(tid>>3)
  const int srow = tid >> 3, scp = tid & 7;
  // q fragments (pre-scaled by C^-0.5*log2e in gemm)
  const u16* qrow = qg + ((size_t)(b * T_ + t0 + l15)) * H_ + quad * 8;
  const bf16x8 qf0 = *(const bf16x8*)qrow;
  const bf16x8 qf1 = *(const bf16x8*)(qrow + 32);
  __bf16* pt = &Pt[wv][0];
  const f32x4 z = {0.f, 0.f, 0.f, 0.f};
  f32x4 o[4];
  float lr[4] = {0.f, 0.f, 0.f, 0.f};
#pragma unroll
  for (int hi = 0; hi < 4; ++hi) o[hi] = z;

  // prologue: stage step st0 into buf 0
  {
    const int s00 = st0 * 64;
#pragma unroll
    for (int jj = 0; jj < 2; ++jj) {
      const int row = jj * 32 + srow;
      const int sc  = scp ^ (row & 7);
      __builtin_amdgcn_global_load_lds(
          (const AS1 unsigned*)(kb0 + (size_t)(s00 + row) * H_ + sc * 8),
          (AS3 unsigned*)(&Ks[0][(jj * 256 + tid) * 8]), 16, 0, 0);
      __builtin_amdgcn_global_load_lds(
          (const AS1 unsigned*)(vb0 + (size_t)row * T_ + s00 + sc * 8),
          (AS3 unsigned*)(&Vs[0][(jj * 256 + tid) * 8]), 16, 0, 0);
    }
  }
  __syncthreads();

#pragma unroll 1
  for (int st = st0; st < stE; ++st) {
    const int cur = (st - st0) & 1;
    if (st + 1 < stE) {  // stage next into other buffer
      const int s1 = (st + 1) * 64;
#pragma unroll
      for (int jj = 0; jj < 2; ++jj) {
        const int row = jj * 32 + srow;
        const int sc  = scp ^ (row & 7);
        __builtin_amdgcn_global_load_lds(
            (const AS1 unsigned*)(kb0 + (size_t)(s1 + row) * H_ + sc * 8),
            (AS3 unsigned*)(&Ks[cur ^ 1][(jj * 256 + tid) * 8]), 16, 0, 0);
        __builtin_amdgcn_global_load_lds(
            (const AS1 unsigned*)(vb0 + (size_t)row * T_ + s1 + sc * 8),
            (AS3 unsigned*)(&Vs[cur ^ 1][(jj * 256 + tid) * 8]), 16, 0, 0);
      }
    }
    // ---- compute on buf cur ----
    const u16* Kc = &Ks[cur][0];
    const u16* Vc = &Vs[cur][0];
    const int sw = (l15 & 7);
    f32x4 s[4];
#pragma unroll
    for (int ni = 0; ni < 4; ++ni) {
      const u16* kr = Kc + (ni * 16 + l15) * 64;
      const bf16x8 k0 = *(const bf16x8*)(kr + ((quad       ^ sw) * 8));
      const bf16x8 k1 = *(const bf16x8*)(kr + (((4 + quad) ^ sw) * 8));
      s[ni] = __builtin_amdgcn_mfma_f32_16x16x32_bf16(qf0, k0, z, 0, 0, 0);
      s[ni] = __builtin_amdgcn_mfma_f32_16x16x32_bf16(qf1, k1, s[ni], 0, 0, 0);
    }
    if (st == u) {  // causal mask (only the tile's final step crosses diagonal)
      const int s0 = st * 64;
#pragma unroll
      for (int ni = 0; ni < 4; ++ni)
#pragma unroll
        for (int r = 0; r < 4; ++r)
          if (s0 + ni * 16 + l15 > t0 + quad * 4 + r) s[ni][r] = -1e30f;
    }
    float p[4][4];
#pragma unroll
    for (int ni = 0; ni < 4; ++ni)
#pragma unroll
      for (int r = 0; r < 4; ++r) p[ni][r] = __builtin_amdgcn_exp2f(s[ni][r]);
#pragma unroll
    for (int r = 0; r < 4; ++r)
      lr[r] += (p[0][r] + p[1][r]) + (p[2][r] + p[3][r]);
    // P: C-layout -> A-layout via per-wave LDS (wave-local fence only)
#pragma unroll
    for (int ni = 0; ni < 4; ++ni)
#pragma unroll
      for (int r = 0; r < 4; ++r)
        pt[(quad * 4 + r) * 72 + ni * 16 + l15] = (__bf16)p[ni][r];
    asm volatile("s_waitcnt lgkmcnt(0)" ::: "memory");
    const bf16x8 pa0 = *(const bf16x8*)(pt + l15 * 72 + quad * 8);
    const bf16x8 pa1 = *(const bf16x8*)(pt + l15 * 72 + 32 + quad * 8);
    asm volatile("" ::: "memory");
#pragma unroll
    for (int hi = 0; hi < 4; ++hi) {
      const u16* vr = Vc + (hi * 16 + l15) * 64;
      const bf16x8 v0 = *(const bf16x8*)(vr + ((quad       ^ sw) * 8));
      const bf16x8 v1 = *(const bf16x8*)(vr + (((4 + quad) ^ sw) * 8));
      o[hi] = __builtin_amdgcn_mfma_f32_16x16x32_bf16(pa0, v0, o[hi], 0, 0, 0);
      o[hi] = __builtin_amdgcn_mfma_f32_16x16x32_bf16(pa1, v1, o[hi], 0, 0, 0);
    }
    __syncthreads();  // everyone done with cur; next-glds drained
  }
  // epilogue: row-sum lr across the 16 lanes of each quad, write f32 partial
#pragma unroll
  for (int d = 1; d < 16; d <<= 1)
#pragma unroll
    for (int r = 0; r < 4; ++r) lr[r] += __shfl_xor(lr[r], d, 64);
  float* po = fpart + (size_t)((b * 128 + qt) * 8 + c) * 1040;
#pragma unroll
  for (int hi = 0; hi < 4; ++hi)
#pragma unroll
    for (int r = 0; r < 4; ++r)
      po[(quad * 4 + r) * 64 + hi * 16 + l15] = o[hi][r];
  if (l15 == 0) {
#pragma unroll
    for (int r = 0; r < 4; ++r) po[1024 + quad * 4 + r] = lr[r];
  }
}

// ---------------------------------------------------------------------------
// freduce: grid (128, 8), block 256. Block (qt, b): sum nc = (qt>>4)+1 chunk
// partials (deterministic order) and normalize by l. Thread t owns float4 at
// element 4t: row = t>>4, cols (4t)&63.  (unchanged from R7)
// ---------------------------------------------------------------------------
__global__ __launch_bounds__(256)
void freduce(const float* __restrict__ fpart, float* __restrict__ out) {
  const int qt  = blockIdx.x;
  const int b   = blockIdx.y;
  const int tid = threadIdx.x;
  const int nc  = (qt >> 4) + 1;  // ceil(((qt>>2)+1)/4)
  const float* __restrict__ pb = fpart + (size_t)(b * 128 + qt) * 8 * 1040;
  __shared__ float ls[16];
  if (tid < 16) {
    float s = 0.f;
#pragma unroll 1
    for (int i = 0; i < nc; ++i) s += pb[(size_t)i * 1040 + 1024 + tid];
    ls[tid] = s;
  }
  __syncthreads();
  f32x4 a = {0.f, 0.f, 0.f, 0.f};
#pragma unroll 1
  for (int i = 0; i < nc; ++i)
    a += *(const f32x4*)(pb + (size_t)i * 1040 + tid * 4);
  const float inv = 1.0f / ls[tid >> 4];
  a[0] *= inv; a[1] *= inv; a[2] *= inv; a[3] *= inv;
  *(f32x4*)(out + (size_t)(b * T_ + qt * 16 + (tid >> 4)) * H_ + ((tid * 4) & 63)) = a;
}

extern "C" void kernel_launch(void* const* d_in, const int* in_sizes, int n_in,
                              void* d_out, int out_size, void* d_ws, size_t ws_size,
                              hipStream_t stream) {
  const float* x  = (const float*)d_in[0];
  const float* Wk = (const float*)d_in[1];
  const float* Wq = (const float*)d_in[2];
  const float* Wv = (const float*)d_in[3];
  u16*   ws  = (u16*)d_ws;
  u16*   Wct = ws + (size_t)3 * BTH;
  float* fpart = (float*)(ws + (size_t)3 * BTH + 192 * 1024);  // 16B-aligned
  float* out = (float*)d_out;
  wpack<<<dim3(3, 16), 256, 0, stream>>>(Wk, Wq, Wv, Wct);
  qkv_gemm<<<dim3(256), 256, 0, stream>>>(x, Wct, ws);
  flash<<<dim3(144, B_), 256, 0, stream>>>(ws, fpart);
  freduce<<<dim3(128, B_), 256, 0, stream>>>(fpart, out);
}